// Round 1
// baseline (1111.744 us; speedup 1.0000x reference)
//
#include <hip/hip_runtime.h>
#include <hip/hip_bf16.h>
#include <cstdint>
#include <cstddef>

// Problem: T=2048, B=64, D=256, H=256, L=2. M = T*B = 131072, K = 256, N = 4H = 1024.

typedef float floatx4 __attribute__((ext_vector_type(4)));
typedef float float4v __attribute__((ext_vector_type(4)));
typedef _Float16 half8 __attribute__((ext_vector_type(8)));

typedef const void GV __attribute__((address_space(1)));
typedef void LV __attribute__((address_space(3)));

__device__ __forceinline__ void async_load16(const void* gsrc, void* ldst) {
  __builtin_amdgcn_global_load_lds((GV*)gsrc, (LV*)ldst, 16, 0, 0);
}

__device__ __forceinline__ float sigm(float x) { return 1.0f / (1.0f + __expf(-x)); }
__device__ __forceinline__ float tanh_(float x) { return 2.0f / (1.0f + __expf(-2.0f * x)) - 1.0f; }

// ---- prep: W[L,4,D+H,H] fp32 -> Wt[L][1024 cols][256 k] fp16, x-part only, permuted cols.
// col(g, oh) = (oh>>4)*64 + g*16 + (oh&15)  -> each wave's 4 ni-fragments are the 4 gates of one oh.
__global__ void prep_wt(const float* __restrict__ W, _Float16* __restrict__ Wt) {
  int idx = blockIdx.x * 256 + threadIdx.x;  // [0, 2*4*256*256)
  int oh = idx & 255;
  int k = (idx >> 8) & 255;
  int g = (idx >> 16) & 3;
  int l = idx >> 18;
  float w = W[(size_t)((l * 4 + g) * 512 + k) * 256 + oh];
  int col = ((oh >> 4) << 6) + (g << 4) + (oh & 15);
  Wt[(size_t)(l * 1024 + col) * 256 + k] = (_Float16)w;
}

// ---- prep: bias_p[l][b][col] = b[l,g,oh] + sum_j h0[l,b,j] * W[l,g,256+j,oh]  (permuted cols)
__global__ void prep_bias(const float* __restrict__ W, const float* __restrict__ bv,
                          const float* __restrict__ h0, float* __restrict__ bias_p) {
  int l = blockIdx.x >> 6, b = blockIdx.x & 63;
  int t = threadIdx.x;  // 256 threads, t == oh
  __shared__ float h0s[256];
  h0s[t] = h0[(l * 64 + b) * 256 + t];
  __syncthreads();
  float acc[4] = {0.f, 0.f, 0.f, 0.f};
  for (int j = 0; j < 256; ++j) {
    float hv = h0s[j];
#pragma unroll
    for (int g = 0; g < 4; ++g)
      acc[g] += hv * W[(size_t)((l * 4 + g) * 512 + 256 + j) * 256 + t];
  }
#pragma unroll
  for (int g = 0; g < 4; ++g) {
    float val = bv[(l * 4 + g) * 256 + t] + acc[g];
    int col = ((t >> 4) << 6) + (g << 4) + (t & 15);
    bias_p[(size_t)(l * 64 + b) * 1024 + col] = val;
  }
}

// ---- main fused GEMM + LSTM-cell epilogue. 256 thr = 4 waves, 128x128 tile, BK=64.
template <int LAYER>
__global__ void lstm_gemm(const float* __restrict__ A, const _Float16* __restrict__ Wt,
                          const float* __restrict__ biasL, const float* __restrict__ c0L,
                          float* __restrict__ out_x, float* __restrict__ out_h,
                          float* __restrict__ out_c) {
  __shared__ alignas(16) char smem[32768];
  _Float16* As = (_Float16*)smem;             // [128][64] fp16, XOR chunk-swizzled
  _Float16* Bs = (_Float16*)(smem + 16384);   // [128][64] fp16, XOR chunk-swizzled
  float* biasS = (float*)smem;                // epilogue overlay [64][128] fp32

  int bid = blockIdx.x;
  int xcd = bid & 7;          // XCD-aware: blocks sharing an A-tile stay on one XCD
  int j = bid >> 3;
  int n_t = j & 7;            // N fast within XCD -> A-tile L2 reuse
  int m_t = (j >> 3) + xcd * 128;
  int Mbase = m_t << 7;
  int Nbase = n_t << 7;

  int tid = threadIdx.x;
  int wave = tid >> 6, lane = tid & 63;
  int wr = wave >> 1, wc = wave & 1;
  int q = lane >> 4, lc = lane & 15;

  // per-thread A row pointers (layer1 reads layer0's h_n slice: row offset ((r>>6)*128+(r&63))*256)
  const float* Arow[4];
#pragma unroll
  for (int it = 0; it < 4; ++it) {
    int r = Mbase + (tid >> 3) + it * 32;
    size_t off = (LAYER == 0) ? (size_t)r * 256 : (size_t)(((r >> 6) * 128) + (r & 63)) * 256;
    Arow[it] = A + off;
  }
  int c8 = tid & 7;
  int pA = (c8 ^ ((tid >> 3) & 7)) * 8;  // swizzled chunk position (row&7 invariant across it)

  floatx4 acc[4][4];
#pragma unroll
  for (int mi = 0; mi < 4; ++mi)
#pragma unroll
    for (int ni = 0; ni < 4; ++ni) acc[mi][ni] = (floatx4)0.0f;

  for (int kt = 0; kt < 256; kt += 64) {
    __syncthreads();
    // B tile: async global->LDS, 16B/lane; LDS dest = uniform base + lane*16
#pragma unroll
    for (int it = 0; it < 4; ++it) {
      int chunk = (wave * 4 + it) * 64 + lane;
      int n = chunk >> 3, p = chunk & 7;
      int cB = p ^ (n & 7);
      async_load16(Wt + (size_t)(Nbase + n) * 256 + kt + cB * 8,
                   (char*)Bs + (wave * 4 + it) * 1024);
    }
    // A tile: fp32 float4 x2 -> fp16 x8 -> ds_write_b128 (swizzled)
#pragma unroll
    for (int it = 0; it < 4; ++it) {
      const float* src = Arow[it] + kt + c8 * 8;
      float4v f0 = *(const float4v*)src;
      float4v f1 = *(const float4v*)(src + 4);
      half8 hv;
      hv[0] = (_Float16)f0.x; hv[1] = (_Float16)f0.y;
      hv[2] = (_Float16)f0.z; hv[3] = (_Float16)f0.w;
      hv[4] = (_Float16)f1.x; hv[5] = (_Float16)f1.y;
      hv[6] = (_Float16)f1.z; hv[7] = (_Float16)f1.w;
      int m = (tid >> 3) + it * 32;
      *(half8*)(As + m * 64 + pA) = hv;
    }
    __syncthreads();
    // compute: 2 k-steps x 16 MFMAs
#pragma unroll
    for (int ks = 0; ks < 2; ++ks) {
      int pp = ((ks * 4 + q) ^ (lc & 7)) * 8;
      half8 av[4], bw[4];
#pragma unroll
      for (int mi = 0; mi < 4; ++mi)
        av[mi] = *(const half8*)(As + (wr * 64 + mi * 16 + lc) * 64 + pp);
#pragma unroll
      for (int ni = 0; ni < 4; ++ni)
        bw[ni] = *(const half8*)(Bs + (wc * 64 + ni * 16 + lc) * 64 + pp);
#pragma unroll
      for (int mi = 0; mi < 4; ++mi)
#pragma unroll
        for (int ni = 0; ni < 4; ++ni)
          acc[mi][ni] = __builtin_amdgcn_mfma_f32_16x16x32_f16(av[mi], bw[ni], acc[mi][ni], 0, 0, 0);
    }
  }

  // ---- epilogue: stage bias slice [64 batches][128 local cols] into LDS
  __syncthreads();
#pragma unroll
  for (int i2 = 0; i2 < 8; ++i2) {
    int i = tid + i2 * 256;
    int b0 = i >> 5, cc = i & 31;
    ((float4v*)biasS)[i] = *(const float4v*)(biasL + (size_t)b0 * 1024 + Nbase + cc * 4);
  }
  __syncthreads();

  // per wave: one timestep t_, all 64 batches; ni == gate index (f,i,g,o), all in-lane.
  int oh = n_t * 32 + wc * 16 + lc;
  int colL = wc * 64 + lc;
  int t_ = m_t * 2 + wr;
  float* hout = out_h + (size_t)(t_ * 2 + LAYER) * 16384 + oh;
  float* cout = out_c + (size_t)(t_ * 2 + LAYER) * 16384 + oh;
  float* xout = out_x + (size_t)t_ * 64 * 256 + oh;  // only used when LAYER==1
#pragma unroll
  for (int mi = 0; mi < 4; ++mi) {
#pragma unroll
    for (int r = 0; r < 4; ++r) {
      int b = mi * 16 + q * 4 + r;  // batch index (rows mod 64)
      float gf = acc[mi][0][r] + biasS[b * 128 + colL];
      float gi = acc[mi][1][r] + biasS[b * 128 + colL + 16];
      float gg = acc[mi][2][r] + biasS[b * 128 + colL + 32];
      float go = acc[mi][3][r] + biasS[b * 128 + colL + 48];
      float f = sigm(gf), ii = sigm(gi), g_ = tanh_(gg), o = sigm(go);
      float c = f * c0L[b * 256 + oh] + ii * g_;
      float h = o * tanh_(c);
      hout[(size_t)b * 256] = h;
      cout[(size_t)b * 256] = c;
      if (LAYER == 1) xout[(size_t)b * 256] = h;
    }
  }
}

extern "C" void kernel_launch(void* const* d_in, const int* in_sizes, int n_in,
                              void* d_out, int out_size, void* d_ws, size_t ws_size,
                              hipStream_t stream) {
  const float* x = (const float*)d_in[0];   // [T,B,D]
  const float* h0 = (const float*)d_in[1];  // [L,B,H]
  const float* c0 = (const float*)d_in[2];  // [L,B,H]
  const float* W = (const float*)d_in[3];   // [L,4,D+H,H]
  const float* bv = (const float*)d_in[4];  // [L,4,H]
  float* out = (float*)d_out;

  char* ws = (char*)d_ws;
  _Float16* Wt = (_Float16*)ws;              // 2*1024*256*2 = 1 MB
  float* bias_p = (float*)(ws + (1 << 20));  // 2*64*1024*4 = 512 KB

  prep_wt<<<2048, 256, 0, stream>>>(W, Wt);
  prep_bias<<<128, 256, 0, stream>>>(W, bv, h0, bias_p);

  float* xout = out;                          // x: [T,B,H]        (33,554,432 floats)
  float* hn = out + (size_t)33554432;         // h_n: [T,L,B,H]    (67,108,864)
  float* cn = hn + (size_t)67108864;          // c_n: [T,L,B,H]

  lstm_gemm<0><<<8192, 256, 0, stream>>>(x, Wt, bias_p, c0, xout, hn, cn);
  lstm_gemm<1><<<8192, 256, 0, stream>>>(hn, Wt + (size_t)1024 * 256,
                                         bias_p + (size_t)64 * 1024, c0 + 64 * 256,
                                         xout, hn, cn);
}